// Round 9
// baseline (308.324 us; speedup 1.0000x reference)
//
#include <hip/hip_runtime.h>
#include <math.h>

#define HH 240
#define WW 240
#define PP (HH * WW)
#define PW 242              // padded height/width for conv input
#define LOG_MAX_C 4.605170185988091f  // log(100)
#define LOG2E 1.442695040888963f

typedef __bf16 bf16x8 __attribute__((ext_vector_type(8)));
typedef float  f32x4  __attribute__((ext_vector_type(4)));

// native v_exp_f32 (2^x) — NOT __exp2f (glibc macro collision on gfx950 build)
#define EXP2F(x) __builtin_amdgcn_exp2f(x)

// ===========================================================================
// Layouts:
//  xs  [row][icb][px][32]      bf16  — conv B-fragment native (r7-verified)
//  wtf [tap][ocb][icb][512]    bf16  — conv A-fragment native
//  xpk/xpv [b*8+h][y][x][4]    fp32  — conv_in K/V output, attention-native
//  fq4     [b*8+h][y][x][4]    fp32  — conv_f Q output
//  knT/qnT/v1T [h][x][y][4]    fp32  — axial_row exports (transposed), they
//      alias xpk/xpv b0/b1 regions which are dead after win0/win1.
// ===========================================================================

__global__ __launch_bounds__(256) void to_xs_pad(
    const float* __restrict__ in, __bf16* __restrict__ xs)
{
    const int p = blockIdx.x * 256 + threadIdx.x;
    if (p >= PW * PW) return;
    const int row = p / PW, px = p % PW;
    const bool border = (row == 0 || row == PW - 1 || px == 0 || px == PW - 1);
    union { __bf16 h[32]; uint4 u[4]; } pk;
#pragma unroll
    for (int icb = 0; icb < 3; ++icb) {
        uint4* op = (uint4*)(xs + (((size_t)row * 3 + icb) * PW + px) * 32);
        if (border) {
#pragma unroll
            for (int b = 0; b < 4; ++b) op[b] = make_uint4(0, 0, 0, 0);
        } else {
            const float* ip = in + (size_t)(icb * 32) * PP + (row - 1) * WW + (px - 1);
#pragma unroll
            for (int j = 0; j < 32; ++j) pk.h[j] = (__bf16)ip[(size_t)j * PP];
#pragma unroll
            for (int b = 0; b < 4; ++b) op[b] = pk.u[b];
        }
    }
}

__global__ __launch_bounds__(256) void wt_frag(
    const float* __restrict__ w, __bf16* __restrict__ wtf, int OC)
{
    const int t = blockIdx.x * 256 + threadIdx.x;
    if (t >= 9 * (OC / 16) * 3 * 64) return;
    const int lane = t & 63;
    const int rest = t >> 6;
    const int icb  = rest % 3;
    const int to   = rest / 3;
    const int ocb  = to % (OC / 16);
    const int tap  = to / (OC / 16);
    const int ln = lane & 15, quad = lane >> 4;
    const int oc  = ocb * 16 + ln;
    const int ic0 = icb * 32 + quad * 8;
    __bf16* op = wtf + (size_t)rest * 512 + lane * 8;
#pragma unroll
    for (int d = 0; d < 8; ++d)
        op[d] = (__bf16)w[(size_t)(oc * 96 + ic0 + d) * 9 + tap];
}

__global__ __launch_bounds__(256) void zero_border_xs(__bf16* __restrict__ ys)
{
    const int idx = blockIdx.x * 256 + threadIdx.x;
    if (idx >= 4 * PW) return;
    const int g = idx / PW, i = idx % PW;
    int row, px;
    if (g == 0)      { row = 0;      px = i; }
    else if (g == 1) { row = PW - 1; px = i; }
    else if (g == 2) { row = i;      px = 0; }
    else             { row = i;      px = PW - 1; }
#pragma unroll
    for (int icb = 0; icb < 3; ++icb) {
        uint4* op = (uint4*)(ys + (((size_t)row * 3 + icb) * PW + px) * 32);
#pragma unroll
        for (int b = 0; b < 4; ++b) op[b] = make_uint4(0, 0, 0, 0);
    }
}

// ---------------------------------------------------------------------------
// Implicit-GEMM 3x3 conv on MFMA (r7-verified core). EPI selects epilogue:
//  0: NCHW fp32 (conv_out -> d_out)
//  1: xpk/xpv [b*8+h][y][x][4] f32x4 stores (conv_in; MT=4, oc-slice 64 = b)
//  2: fq4 [b*8+h][y][x][4] (conv_f; MT=2, oc-slice 32 = b)
// oc = oc0 + mi*16 + quad*4 + r  ->  kv=mi>>1 (EPI1), h=(mi&1)*4+quad (EPI1)
// or h=mi*4+quad (EPI2), d=r (= acc vector lane, so one f32x4 store).
// ---------------------------------------------------------------------------
template <int OC, int MT, int EPI>
__global__ __launch_bounds__(256) void conv3x3_mfma(
    const __bf16* __restrict__ xs, const __bf16* __restrict__ wtf,
    const float* __restrict__ bias, float* __restrict__ out0,
    float* __restrict__ out1)
{
    const int bid   = blockIdx.x;
    const int group = bid / 24;
    const int w24   = bid % 24;
    const int z     = w24 >> 3;
    const int xy    = group * 8 + (w24 & 7);
    if (xy >= 450) return;
    const int x0  = (xy % 15) * 16;
    const int y0  = (xy / 15) * 8;
    const int oc0 = z * (MT * 16);
    const int ocb0 = oc0 / 16;

    const int wave = threadIdx.x >> 6;
    const int lane = threadIdx.x & 63;
    const int ln   = lane & 15;
    const int quad = lane >> 4;
    const int r0   = y0 + wave * 2;

    f32x4 acc[MT][2] = {};
    bf16x8 a[2][MT], b[2][2];

    const __bf16* abase = wtf + (size_t)lane * 8;
    const __bf16* bbase = xs + (size_t)ln * 32 + quad * 8;

#define LOAD_CHUNK(c, buf)                                                    \
    {                                                                         \
        const int tap_ = (c) / 3, icb_ = (c) % 3;                             \
        const int dy_ = tap_ / 3, dx_ = tap_ % 3;                             \
        const __bf16* ap_ = abase + (size_t)((tap_ * (OC / 16) + ocb0) * 3 + icb_) * 512; \
        _Pragma("unroll")                                                     \
        for (int mi = 0; mi < MT; ++mi)                                       \
            a[buf][mi] = *(const bf16x8*)(ap_ + (size_t)mi * 1536);           \
        _Pragma("unroll")                                                     \
        for (int ni = 0; ni < 2; ++ni)                                        \
            b[buf][ni] = *(const bf16x8*)(bbase +                             \
                (((size_t)(r0 + ni + dy_) * 3 + icb_) * PW + x0 + dx_) * 32); \
    }

    LOAD_CHUNK(0, 0)
#pragma unroll
    for (int c = 0; c < 27; ++c) {
        const int cur = c & 1, nxt = cur ^ 1;
        if (c < 26) LOAD_CHUNK(c + 1, nxt)
#pragma unroll
        for (int mi = 0; mi < MT; ++mi)
#pragma unroll
            for (int ni = 0; ni < 2; ++ni)
                acc[mi][ni] = __builtin_amdgcn_mfma_f32_16x16x32_bf16(
                    a[cur][mi], b[cur][ni], acc[mi][ni], 0, 0, 0);
    }
#undef LOAD_CHUNK

    if constexpr (EPI == 0) {
#pragma unroll
        for (int mi = 0; mi < MT; ++mi) {
#pragma unroll
            for (int r = 0; r < 4; ++r) {
                const int oc = oc0 + mi * 16 + quad * 4 + r;
                const float bv = bias[oc];
#pragma unroll
                for (int ni = 0; ni < 2; ++ni)
                    out0[(size_t)oc * PP + (r0 + ni) * WW + x0 + ln] = acc[mi][ni][r] + bv;
            }
        }
    } else if constexpr (EPI == 1) {
#pragma unroll
        for (int mi = 0; mi < MT; ++mi) {
            const f32x4 bv = *(const f32x4*)(bias + oc0 + mi * 16 + quad * 4);
            float* dst = (mi >> 1) ? out1 : out0;
            const int h8 = z * 8 + (mi & 1) * 4 + quad;
#pragma unroll
            for (int ni = 0; ni < 2; ++ni) {
                f32x4 o = acc[mi][ni] + bv;
                *(f32x4*)(dst + (((size_t)h8 * 240 + r0 + ni) * 240 + x0 + ln) * 4) = o;
            }
        }
    } else {
#pragma unroll
        for (int mi = 0; mi < MT; ++mi) {
            const f32x4 bv = *(const f32x4*)(bias + oc0 + mi * 16 + quad * 4);
            const int h8 = z * 8 + mi * 4 + quad;
#pragma unroll
            for (int ni = 0; ni < 2; ++ni) {
                f32x4 o = acc[mi][ni] + bv;
                *(f32x4*)(out0 + (((size_t)h8 * 240 + r0 + ni) * 240 + x0 + ln) * 4) = o;
            }
        }
    }
}

// ---------------------------------------------------------------------------
// Window cosine attention. Staging now 3 coalesced-ish f32x4 loads (was 12
// divergent dwords). Fixed-max single-pass softmax (r4-verified). XCD swizzle.
// ---------------------------------------------------------------------------
__global__ __launch_bounds__(256) void win_attn_kernel(
    const float* __restrict__ fq4b, const float* __restrict__ xpkb,
    const float* __restrict__ xpvb, const float* __restrict__ lsc,
    __bf16* __restrict__ ys, int gshift, int sshift, int icb)
{
    __shared__ f32x4 ks[8][25];
    __shared__ f32x4 vs[8][25];
    const int bid = blockIdx.x;
    const int wi  = bid / 288;
    const int g   = bid % 288;
    const int wy  = g / 6;
    const int wx  = (g % 6) * 8 + wi;
    const int t = threadIdx.x;
    const int h = t / 25, i = t % 25;
    f32x4 qn = {0, 0, 0, 0};
    float negM2 = 0.f;
    int oy = 0, ox = 0;

    if (t < 200) {
        const int y = (wy * 5 + i / 5 + gshift) % HH;
        const int x = (wx * 5 + i % 5 + gshift) % WW;
        const size_t p4 = (((size_t)h * 240 + y) * 240 + x) * 4;
        const f32x4 q = *(const f32x4*)(fq4b + p4);
        const f32x4 k = *(const f32x4*)(xpkb + p4);
        vs[h][i] = *(const f32x4*)(xpvb + p4);
        const float qsq = q[0]*q[0] + q[1]*q[1] + q[2]*q[2] + q[3]*q[3];
        const float ksq = k[0]*k[0] + k[1]*k[1] + k[2]*k[2] + k[3]*k[3];
        const float scale = __expf(fminf(lsc[h], LOG_MAX_C));
        const float qs = scale * LOG2E;
        negM2 = -qs;
        const float qinv = qs / fmaxf(sqrtf(qsq), 1e-12f);
        const float kinv = 1.0f / fmaxf(sqrtf(ksq), 1e-12f);
        qn = q * qinv;
        ks[h][i] = k * kinv;
        oy = (wy * 5 + i / 5 + sshift) % HH;
        ox = (wx * 5 + i % 5 + sshift) % WW;
    }
    __syncthreads();
    if (t < 200) {
        float l = 0.f;
        f32x4 acc = {0, 0, 0, 0};
#pragma unroll
        for (int j = 0; j < 25; ++j) {
            const f32x4 kk = ks[h][j];
            const float s = fmaf(qn[0], kk[0],
                            fmaf(qn[1], kk[1],
                            fmaf(qn[2], kk[2],
                            fmaf(qn[3], kk[3], negM2))));
            const float p = EXP2F(s);
            l += p;
            acc += vs[h][j] * p;
        }
        const float linv = 1.0f / l;
        union { __bf16 h4[4]; uint2 u; } o;
#pragma unroll
        for (int d = 0; d < 4; ++d) o.h4[d] = (__bf16)(acc[d] * linv);
        *(uint2*)(ys + (((size_t)(oy + 1) * 3 + icb) * PW + ox + 1) * 32 + h * 4) = o.u;
    }
}

// ---------------------------------------------------------------------------
// Axial row attention (over w). Block (y,h), 128 threads, 2 queries/thread
// (x = t, t+120): LDS k/v reads amortized over 2 queries. Exports normalized
// kn, scaled qn, and row output v1, all TRANSPOSED [h][x][y][4] so axial_col
// stages coalesced (stores are divergent but fire-and-forget).
// ---------------------------------------------------------------------------
__global__ __launch_bounds__(128) void axial_row_kernel(
    const float* __restrict__ fq4b, const float* __restrict__ xpkb,
    const float* __restrict__ xpvb, const float* __restrict__ lsc,
    float* __restrict__ knT, float* __restrict__ qnT, float* __restrict__ v1T)
{
    __shared__ f32x4 ks[240];
    __shared__ f32x4 vs[240];
    const int t = threadIdx.x;
    const int y = blockIdx.x, h = blockIdx.y;

    const float scale = __expf(fminf(lsc[h], LOG_MAX_C));
    const float qs = scale * LOG2E;
    const float negM2 = -qs;
    f32x4 qreg[2];

    if (t < 120) {
#pragma unroll
        for (int s = 0; s < 2; ++s) {
            const int xx = t + s * 120;
            const size_t p4 = (((size_t)h * 240 + y) * 240 + xx) * 4;
            const f32x4 k = *(const f32x4*)(xpkb + p4);
            const f32x4 v = *(const f32x4*)(xpvb + p4);
            const f32x4 q = *(const f32x4*)(fq4b + p4);
            const float ksq = k[0]*k[0] + k[1]*k[1] + k[2]*k[2] + k[3]*k[3];
            const float qsq = q[0]*q[0] + q[1]*q[1] + q[2]*q[2] + q[3]*q[3];
            const float kinv = 1.0f / fmaxf(sqrtf(ksq), 1e-12f);
            const float qinv = qs / fmaxf(sqrtf(qsq), 1e-12f);
            const f32x4 kn = k * kinv;
            const f32x4 qn = q * qinv;
            ks[xx] = kn;
            vs[xx] = v;
            qreg[s] = qn;
            const size_t pT = (((size_t)h * 240 + xx) * 240 + y) * 4;
            *(f32x4*)(knT + pT) = kn;
            *(f32x4*)(qnT + pT) = qn;
        }
    }
    __syncthreads();
    if (t < 120) {
        float l0 = 0.f, l1 = 0.f;
        f32x4 a0 = {0, 0, 0, 0}, a1 = {0, 0, 0, 0};
#pragma unroll 2
        for (int j = 0; j < 240; ++j) {
            const f32x4 kk = ks[j];
            const f32x4 vv = vs[j];
            const float s0 = fmaf(qreg[0][0], kk[0],
                             fmaf(qreg[0][1], kk[1],
                             fmaf(qreg[0][2], kk[2],
                             fmaf(qreg[0][3], kk[3], negM2))));
            const float s1 = fmaf(qreg[1][0], kk[0],
                             fmaf(qreg[1][1], kk[1],
                             fmaf(qreg[1][2], kk[2],
                             fmaf(qreg[1][3], kk[3], negM2))));
            const float p0 = EXP2F(s0);
            const float p1 = EXP2F(s1);
            l0 += p0; l1 += p1;
            a0 += vv * p0;
            a1 += vv * p1;
        }
        const float li0 = 1.0f / l0, li1 = 1.0f / l1;
        const f32x4 o0 = a0 * li0, o1 = a1 * li1;
        *(f32x4*)(v1T + (((size_t)h * 240 + t) * 240 + y) * 4) = o0;
        *(f32x4*)(v1T + (((size_t)h * 240 + t + 120) * 240 + y) * 4) = o1;
    }
}

// ---------------------------------------------------------------------------
// Axial column attention (over h). Block (x,h) via XCD swizzle (r8-verified:
// FETCH 93->12 MB), 128 threads, 2 queries/thread. All staging loads are
// coalesced f32x4 from the transposed exports; no renormalization (identical
// arithmetic to before, computed once in axial_row).
// ---------------------------------------------------------------------------
__global__ __launch_bounds__(128) void axial_col_kernel(
    const float* __restrict__ knT, const float* __restrict__ qnT,
    const float* __restrict__ v1T, const float* __restrict__ lsc,
    __bf16* __restrict__ ys)
{
    __shared__ f32x4 ks[240];
    __shared__ f32x4 vs[240];
    const int bid = blockIdx.x;
    const int wi  = bid / 120;
    const int g   = bid % 120;
    const int h   = g % 8;
    const int x   = (g / 8) * 16 + wi;
    const int t = threadIdx.x;

    const float scale = __expf(fminf(lsc[h], LOG_MAX_C));
    const float negM2 = -scale * LOG2E;
    f32x4 qreg[2] = {};

    if (t < 120) {
#pragma unroll
        for (int s = 0; s < 2; ++s) {
            const int jj = t + s * 120;
            const size_t pT = (((size_t)h * 240 + x) * 240 + jj) * 4;
            ks[jj] = *(const f32x4*)(knT + pT);
            vs[jj] = *(const f32x4*)(v1T + pT);
            qreg[s] = *(const f32x4*)(qnT + pT);
        }
    }
    __syncthreads();
    if (t < 120) {
        float l0 = 0.f, l1 = 0.f;
        f32x4 a0 = {0, 0, 0, 0}, a1 = {0, 0, 0, 0};
#pragma unroll 2
        for (int j = 0; j < 240; ++j) {
            const f32x4 kk = ks[j];
            const f32x4 vv = vs[j];
            const float s0 = fmaf(qreg[0][0], kk[0],
                             fmaf(qreg[0][1], kk[1],
                             fmaf(qreg[0][2], kk[2],
                             fmaf(qreg[0][3], kk[3], negM2))));
            const float s1 = fmaf(qreg[1][0], kk[0],
                             fmaf(qreg[1][1], kk[1],
                             fmaf(qreg[1][2], kk[2],
                             fmaf(qreg[1][3], kk[3], negM2))));
            const float p0 = EXP2F(s0);
            const float p1 = EXP2F(s1);
            l0 += p0; l1 += p1;
            a0 += vv * p0;
            a1 += vv * p1;
        }
        const float li0 = 1.0f / l0, li1 = 1.0f / l1;
#pragma unroll
        for (int s = 0; s < 2; ++s) {
            const f32x4 o4 = (s ? a1 * li1 : a0 * li0);
            const int i = t + s * 120;
            union { __bf16 h4[4]; uint2 u; } o;
#pragma unroll
            for (int d = 0; d < 4; ++d) o.h4[d] = (__bf16)o4[d];
            *(uint2*)(ys + (((size_t)(i + 1) * 3 + 2) * PW + x + 1) * 32 + h * 4) = o.u;
        }
    }
}

// ---------------------------------------------------------------------------
// Pipeline. Workspace (fp32 units):
//   xpk 96PP | xpv 96PP | fq4 96PP | xs/ys bf16 | wtf_in | wtf_f | wtf_o
// Aliases (dead-region reuse, launch order guarantees safety):
//   knT = xpk[b0], v1T = xpv[b0]  (dead after win0)
//   qnT = xpk[b1]                 (dead after win1)
// ---------------------------------------------------------------------------
extern "C" void kernel_launch(void* const* d_in, const int* in_sizes, int n_in,
                              void* d_out, int out_size, void* d_ws, size_t ws_size,
                              hipStream_t stream)
{
    const float* x     = (const float*)d_in[0];
    const float* w_in  = (const float*)d_in[1];
    const float* b_in  = (const float*)d_in[2];
    const float* w_f   = (const float*)d_in[3];
    const float* b_f   = (const float*)d_in[4];
    const float* w_out = (const float*)d_in[5];
    const float* b_out = (const float*)d_in[6];
    const float* lsc   = (const float*)d_in[7];
    const float* lrlsc = (const float*)d_in[8];
    float* out = (float*)d_out;

    float* ws  = (float*)d_ws;
    float* xpk = ws;                   // 96*PP
    float* xpv = xpk + 96 * PP;        // 96*PP
    float* fq4 = xpv + 96 * PP;        // 96*PP
    __bf16* xs     = (__bf16*)(fq4 + 96 * PP);            // 242*3*242*32 bf16
    __bf16* wtf_in = xs + (size_t)PW * 3 * PW * 32;
    __bf16* wtf_f  = wtf_in + 9 * 12 * 3 * 512;
    __bf16* wtf_o  = wtf_f + 9 * 6 * 3 * 512;
    __bf16* ys     = xs;               // alias: xs dead after conv_in/conv_f

    float* knT = xpk;                  // alias b0 (dead after win0)
    float* v1T = xpv;                  // alias b0 (dead after win0)
    float* qnT = xpk + 32 * PP;        // alias b1 (dead after win1)

    wt_frag<<<(9 * 12 * 3 * 64 + 255) / 256, 256, 0, stream>>>(w_in, wtf_in, 192);
    wt_frag<<<(9 * 6 * 3 * 64 + 255) / 256, 256, 0, stream>>>(w_f, wtf_f, 96);
    wt_frag<<<(9 * 6 * 3 * 64 + 255) / 256, 256, 0, stream>>>(w_out, wtf_o, 96);
    to_xs_pad<<<(PW * PW + 255) / 256, 256, 0, stream>>>(x, xs);

    conv3x3_mfma<192, 4, 1><<<1368, 256, 0, stream>>>(xs, wtf_in, b_in, xpk, xpv);
    conv3x3_mfma<96, 2, 2><<<1368, 256, 0, stream>>>(xs, wtf_f, b_f, fq4, nullptr);

    zero_border_xs<<<(4 * PW + 255) / 256, 256, 0, stream>>>(ys);

    win_attn_kernel<<<2304, 256, 0, stream>>>(fq4, xpk, xpv, lsc, ys, 0, 0, 0);
    win_attn_kernel<<<2304, 256, 0, stream>>>(fq4 + 32 * PP, xpk + 32 * PP,
                                              xpv + 32 * PP, lsc, ys, 3, 2, 1);
    axial_row_kernel<<<dim3(240, 8), 128, 0, stream>>>(
        fq4 + 64 * PP, xpk + 64 * PP, xpv + 64 * PP, lrlsc, knT, qnT, v1T);
    axial_col_kernel<<<1920, 128, 0, stream>>>(knT, qnT, v1T, lrlsc, ys);

    conv3x3_mfma<96, 2, 0><<<1368, 256, 0, stream>>>(ys, wtf_o, b_out, out, nullptr);
}

// Round 10
// 299.997 us; speedup vs baseline: 1.0278x; 1.0278x over previous
//
#include <hip/hip_runtime.h>
#include <math.h>

#define HH 240
#define WW 240
#define PP (HH * WW)
#define PW 242              // padded height/width for conv input
#define LOG_MAX_C 4.605170185988091f  // log(100)
#define LOG2E 1.442695040888963f

typedef __bf16 bf16x8 __attribute__((ext_vector_type(8)));
typedef float  f32x4  __attribute__((ext_vector_type(4)));

// native v_exp_f32 (2^x) — NOT __exp2f (glibc macro collision on gfx950 build)
#define EXP2F(x) __builtin_amdgcn_exp2f(x)

// ===========================================================================
// Layouts:
//  xs  [row][icb][px][32]      bf16  — conv B-fragment native (r7-verified)
//  wtf [tap][ocb][icb][512]    bf16  — conv A-fragment native
//  xpk/xpv [b*8+h][y][x][4]    fp32  — conv_in K/V output, attention-native
//  fq4     [b*8+h][y][x][4]    fp32  — conv_f Q output
//  kn/qn/v1   [h][y][x][4]     fp32  — axial_row exports, NATURAL layout
//      (r9 post-mortem: transposed per-block exports caused 2x partial-line
//       write amplification, 43 MB -> axial_row write-bound at 53 us)
//  knT/qnT/v1T [h][x][y][4]    fp32  — produced by transpose3 (LDS-tiled,
//      all line writers within one block -> coalesced both sides)
// ===========================================================================

__global__ __launch_bounds__(256) void to_xs_pad(
    const float* __restrict__ in, __bf16* __restrict__ xs)
{
    const int p = blockIdx.x * 256 + threadIdx.x;
    if (p >= PW * PW) return;
    const int row = p / PW, px = p % PW;
    const bool border = (row == 0 || row == PW - 1 || px == 0 || px == PW - 1);
    union { __bf16 h[32]; uint4 u[4]; } pk;
#pragma unroll
    for (int icb = 0; icb < 3; ++icb) {
        uint4* op = (uint4*)(xs + (((size_t)row * 3 + icb) * PW + px) * 32);
        if (border) {
#pragma unroll
            for (int b = 0; b < 4; ++b) op[b] = make_uint4(0, 0, 0, 0);
        } else {
            const float* ip = in + (size_t)(icb * 32) * PP + (row - 1) * WW + (px - 1);
#pragma unroll
            for (int j = 0; j < 32; ++j) pk.h[j] = (__bf16)ip[(size_t)j * PP];
#pragma unroll
            for (int b = 0; b < 4; ++b) op[b] = pk.u[b];
        }
    }
}

__global__ __launch_bounds__(256) void wt_frag(
    const float* __restrict__ w, __bf16* __restrict__ wtf, int OC)
{
    const int t = blockIdx.x * 256 + threadIdx.x;
    if (t >= 9 * (OC / 16) * 3 * 64) return;
    const int lane = t & 63;
    const int rest = t >> 6;
    const int icb  = rest % 3;
    const int to   = rest / 3;
    const int ocb  = to % (OC / 16);
    const int tap  = to / (OC / 16);
    const int ln = lane & 15, quad = lane >> 4;
    const int oc  = ocb * 16 + ln;
    const int ic0 = icb * 32 + quad * 8;
    __bf16* op = wtf + (size_t)rest * 512 + lane * 8;
#pragma unroll
    for (int d = 0; d < 8; ++d)
        op[d] = (__bf16)w[(size_t)(oc * 96 + ic0 + d) * 9 + tap];
}

__global__ __launch_bounds__(256) void zero_border_xs(__bf16* __restrict__ ys)
{
    const int idx = blockIdx.x * 256 + threadIdx.x;
    if (idx >= 4 * PW) return;
    const int g = idx / PW, i = idx % PW;
    int row, px;
    if (g == 0)      { row = 0;      px = i; }
    else if (g == 1) { row = PW - 1; px = i; }
    else if (g == 2) { row = i;      px = 0; }
    else             { row = i;      px = PW - 1; }
#pragma unroll
    for (int icb = 0; icb < 3; ++icb) {
        uint4* op = (uint4*)(ys + (((size_t)row * 3 + icb) * PW + px) * 32);
#pragma unroll
        for (int b = 0; b < 4; ++b) op[b] = make_uint4(0, 0, 0, 0);
    }
}

// ---------------------------------------------------------------------------
// Implicit-GEMM 3x3 conv on MFMA (r7-verified core). EPI selects epilogue:
//  0: NCHW fp32 (conv_out)   1: xpk/xpv f32x4 (conv_in)   2: fq4 (conv_f)
// ---------------------------------------------------------------------------
template <int OC, int MT, int EPI>
__global__ __launch_bounds__(256) void conv3x3_mfma(
    const __bf16* __restrict__ xs, const __bf16* __restrict__ wtf,
    const float* __restrict__ bias, float* __restrict__ out0,
    float* __restrict__ out1)
{
    const int bid   = blockIdx.x;
    const int group = bid / 24;
    const int w24   = bid % 24;
    const int z     = w24 >> 3;
    const int xy    = group * 8 + (w24 & 7);
    if (xy >= 450) return;
    const int x0  = (xy % 15) * 16;
    const int y0  = (xy / 15) * 8;
    const int oc0 = z * (MT * 16);
    const int ocb0 = oc0 / 16;

    const int wave = threadIdx.x >> 6;
    const int lane = threadIdx.x & 63;
    const int ln   = lane & 15;
    const int quad = lane >> 4;
    const int r0   = y0 + wave * 2;

    f32x4 acc[MT][2] = {};
    bf16x8 a[2][MT], b[2][2];

    const __bf16* abase = wtf + (size_t)lane * 8;
    const __bf16* bbase = xs + (size_t)ln * 32 + quad * 8;

#define LOAD_CHUNK(c, buf)                                                    \
    {                                                                         \
        const int tap_ = (c) / 3, icb_ = (c) % 3;                             \
        const int dy_ = tap_ / 3, dx_ = tap_ % 3;                             \
        const __bf16* ap_ = abase + (size_t)((tap_ * (OC / 16) + ocb0) * 3 + icb_) * 512; \
        _Pragma("unroll")                                                     \
        for (int mi = 0; mi < MT; ++mi)                                       \
            a[buf][mi] = *(const bf16x8*)(ap_ + (size_t)mi * 1536);           \
        _Pragma("unroll")                                                     \
        for (int ni = 0; ni < 2; ++ni)                                        \
            b[buf][ni] = *(const bf16x8*)(bbase +                             \
                (((size_t)(r0 + ni + dy_) * 3 + icb_) * PW + x0 + dx_) * 32); \
    }

    LOAD_CHUNK(0, 0)
#pragma unroll
    for (int c = 0; c < 27; ++c) {
        const int cur = c & 1, nxt = cur ^ 1;
        if (c < 26) LOAD_CHUNK(c + 1, nxt)
#pragma unroll
        for (int mi = 0; mi < MT; ++mi)
#pragma unroll
            for (int ni = 0; ni < 2; ++ni)
                acc[mi][ni] = __builtin_amdgcn_mfma_f32_16x16x32_bf16(
                    a[cur][mi], b[cur][ni], acc[mi][ni], 0, 0, 0);
    }
#undef LOAD_CHUNK

    if constexpr (EPI == 0) {
#pragma unroll
        for (int mi = 0; mi < MT; ++mi) {
#pragma unroll
            for (int r = 0; r < 4; ++r) {
                const int oc = oc0 + mi * 16 + quad * 4 + r;
                const float bv = bias[oc];
#pragma unroll
                for (int ni = 0; ni < 2; ++ni)
                    out0[(size_t)oc * PP + (r0 + ni) * WW + x0 + ln] = acc[mi][ni][r] + bv;
            }
        }
    } else if constexpr (EPI == 1) {
#pragma unroll
        for (int mi = 0; mi < MT; ++mi) {
            const f32x4 bv = *(const f32x4*)(bias + oc0 + mi * 16 + quad * 4);
            float* dst = (mi >> 1) ? out1 : out0;
            const int h8 = z * 8 + (mi & 1) * 4 + quad;
#pragma unroll
            for (int ni = 0; ni < 2; ++ni) {
                f32x4 o = acc[mi][ni] + bv;
                *(f32x4*)(dst + (((size_t)h8 * 240 + r0 + ni) * 240 + x0 + ln) * 4) = o;
            }
        }
    } else {
#pragma unroll
        for (int mi = 0; mi < MT; ++mi) {
            const f32x4 bv = *(const f32x4*)(bias + oc0 + mi * 16 + quad * 4);
            const int h8 = z * 8 + mi * 4 + quad;
#pragma unroll
            for (int ni = 0; ni < 2; ++ni) {
                f32x4 o = acc[mi][ni] + bv;
                *(f32x4*)(out0 + (((size_t)h8 * 240 + r0 + ni) * 240 + x0 + ln) * 4) = o;
            }
        }
    }
}

// ---------------------------------------------------------------------------
// Window cosine attention, branches 0+1 FUSED in one launch (4608 blocks).
// br = bid/2304 selects branch (channel slice, shifts, icb); 2304%8==0 keeps
// the XCD swizzle property on the low bits. Fixed-max single-pass softmax.
// ---------------------------------------------------------------------------
__global__ __launch_bounds__(256) void win_attn_kernel(
    const float* __restrict__ fq4, const float* __restrict__ xpk,
    const float* __restrict__ xpv, const float* __restrict__ lsc,
    __bf16* __restrict__ ys)
{
    __shared__ f32x4 ks[8][25];
    __shared__ f32x4 vs[8][25];
    const int bid = blockIdx.x;
    const int br  = bid / 2304;          // 0: plain, 1: shifted
    const int id  = bid % 2304;
    const int wi  = id / 288;
    const int g   = id % 288;
    const int wy  = g / 6;
    const int wx  = (g % 6) * 8 + wi;
    const int gshift = br * 3, sshift = br * 2;
    const size_t choff = (size_t)br * 32 * PP;
    const int t = threadIdx.x;
    const int h = t / 25, i = t % 25;
    f32x4 qn = {0, 0, 0, 0};
    float negM2 = 0.f;
    int oy = 0, ox = 0;

    if (t < 200) {
        const int y = (wy * 5 + i / 5 + gshift) % HH;
        const int x = (wx * 5 + i % 5 + gshift) % WW;
        const size_t p4 = choff + (((size_t)h * 240 + y) * 240 + x) * 4;
        const f32x4 q = *(const f32x4*)(fq4 + p4);
        const f32x4 k = *(const f32x4*)(xpk + p4);
        vs[h][i] = *(const f32x4*)(xpv + p4);
        const float qsq = q[0]*q[0] + q[1]*q[1] + q[2]*q[2] + q[3]*q[3];
        const float ksq = k[0]*k[0] + k[1]*k[1] + k[2]*k[2] + k[3]*k[3];
        const float scale = __expf(fminf(lsc[h], LOG_MAX_C));
        const float qs = scale * LOG2E;
        negM2 = -qs;
        const float qinv = qs / fmaxf(sqrtf(qsq), 1e-12f);
        const float kinv = 1.0f / fmaxf(sqrtf(ksq), 1e-12f);
        qn = q * qinv;
        ks[h][i] = k * kinv;
        oy = (wy * 5 + i / 5 + sshift) % HH;
        ox = (wx * 5 + i % 5 + sshift) % WW;
    }
    __syncthreads();
    if (t < 200) {
        float l = 0.f;
        f32x4 acc = {0, 0, 0, 0};
#pragma unroll
        for (int j = 0; j < 25; ++j) {
            const f32x4 kk = ks[h][j];
            const float s = fmaf(qn[0], kk[0],
                            fmaf(qn[1], kk[1],
                            fmaf(qn[2], kk[2],
                            fmaf(qn[3], kk[3], negM2))));
            const float p = EXP2F(s);
            l += p;
            acc += vs[h][j] * p;
        }
        const float linv = 1.0f / l;
        union { __bf16 h4[4]; uint2 u; } o;
#pragma unroll
        for (int d = 0; d < 4; ++d) o.h4[d] = (__bf16)(acc[d] * linv);
        *(uint2*)(ys + (((size_t)(oy + 1) * 3 + br) * PW + ox + 1) * 32 + h * 4) = o.u;
    }
}

// ---------------------------------------------------------------------------
// Axial row attention (over w). Block (y,h), 128 threads, 2 queries/thread.
// Exports kn/qn/v1 in NATURAL [h][y][x][4] layout: stores are contiguous
// f32x4 across consecutive x -> fully coalesced, no write amplification
// (r9: transposed per-block stores cost 43 MB WRITE, write-bound).
// ---------------------------------------------------------------------------
__global__ __launch_bounds__(128) void axial_row_kernel(
    const float* __restrict__ fq4b, const float* __restrict__ xpkb,
    const float* __restrict__ xpvb, const float* __restrict__ lsc,
    float* __restrict__ kn, float* __restrict__ qn, float* __restrict__ v1)
{
    __shared__ f32x4 ks[240];
    __shared__ f32x4 vs[240];
    const int t = threadIdx.x;
    const int y = blockIdx.x, h = blockIdx.y;

    const float scale = __expf(fminf(lsc[h], LOG_MAX_C));
    const float qs = scale * LOG2E;
    const float negM2 = -qs;
    f32x4 qreg[2];

    if (t < 120) {
#pragma unroll
        for (int s = 0; s < 2; ++s) {
            const int xx = t + s * 120;
            const size_t p4 = (((size_t)h * 240 + y) * 240 + xx) * 4;
            const f32x4 k = *(const f32x4*)(xpkb + p4);
            const f32x4 v = *(const f32x4*)(xpvb + p4);
            const f32x4 q = *(const f32x4*)(fq4b + p4);
            const float ksq = k[0]*k[0] + k[1]*k[1] + k[2]*k[2] + k[3]*k[3];
            const float qsq = q[0]*q[0] + q[1]*q[1] + q[2]*q[2] + q[3]*q[3];
            const float kinv = 1.0f / fmaxf(sqrtf(ksq), 1e-12f);
            const float qinv = qs / fmaxf(sqrtf(qsq), 1e-12f);
            const f32x4 knv = k * kinv;
            const f32x4 qnv = q * qinv;
            ks[xx] = knv;
            vs[xx] = v;
            qreg[s] = qnv;
            *(f32x4*)(kn + p4) = knv;
            *(f32x4*)(qn + p4) = qnv;
        }
    }
    __syncthreads();
    if (t < 120) {
        float l0 = 0.f, l1 = 0.f;
        f32x4 a0 = {0, 0, 0, 0}, a1 = {0, 0, 0, 0};
#pragma unroll 2
        for (int j = 0; j < 240; ++j) {
            const f32x4 kk = ks[j];
            const f32x4 vv = vs[j];
            const float s0 = fmaf(qreg[0][0], kk[0],
                             fmaf(qreg[0][1], kk[1],
                             fmaf(qreg[0][2], kk[2],
                             fmaf(qreg[0][3], kk[3], negM2))));
            const float s1 = fmaf(qreg[1][0], kk[0],
                             fmaf(qreg[1][1], kk[1],
                             fmaf(qreg[1][2], kk[2],
                             fmaf(qreg[1][3], kk[3], negM2))));
            const float p0 = EXP2F(s0);
            const float p1 = EXP2F(s1);
            l0 += p0; l1 += p1;
            a0 += vv * p0;
            a1 += vv * p1;
        }
        const float li0 = 1.0f / l0, li1 = 1.0f / l1;
        const f32x4 o0 = a0 * li0, o1 = a1 * li1;
        const size_t pr = (((size_t)h * 240 + y) * 240) * 4;
        *(f32x4*)(v1 + pr + (size_t)t * 4) = o0;
        *(f32x4*)(v1 + pr + (size_t)(t + 120) * 4) = o1;
    }
}

// ---------------------------------------------------------------------------
// LDS-tiled (y,x)-transpose of 3 tensors [8][240][240][4] f32 -> [8][240][240][4].
// 16x16 f32x4 tiles, 17-padded rows (2-way LDS aliasing only = free, m136).
// Reads and writes both coalesced; all writers of a 64B line in one block.
// ---------------------------------------------------------------------------
__global__ __launch_bounds__(256) void transpose3(
    const float* __restrict__ a0, const float* __restrict__ a1,
    const float* __restrict__ a2, float* __restrict__ t0,
    float* __restrict__ t1, float* __restrict__ t2)
{
    __shared__ f32x4 tile[16][17];
    const int t = threadIdx.x, ty = t >> 4, tx = t & 15;
    const int h = blockIdx.z, y0 = blockIdx.y * 16, x0 = blockIdx.x * 16;
    const size_t rd = (((size_t)h * 240 + y0 + ty) * 240 + x0 + tx) * 4;
    const size_t wr = (((size_t)h * 240 + x0 + ty) * 240 + y0 + tx) * 4;
    const float* srcs[3] = {a0, a1, a2};
    float* dsts[3] = {t0, t1, t2};
#pragma unroll
    for (int n = 0; n < 3; ++n) {
        tile[ty][tx] = *(const f32x4*)(srcs[n] + rd);
        __syncthreads();
        *(f32x4*)(dsts[n] + wr) = tile[tx][ty];
        __syncthreads();
    }
}

// ---------------------------------------------------------------------------
// Axial column attention (over h). XCD swizzle (r8-verified), 128 threads,
// 2 queries/thread, coalesced staging from transposed exports (r9-verified).
// ---------------------------------------------------------------------------
__global__ __launch_bounds__(128) void axial_col_kernel(
    const float* __restrict__ knT, const float* __restrict__ qnT,
    const float* __restrict__ v1T, const float* __restrict__ lsc,
    __bf16* __restrict__ ys)
{
    __shared__ f32x4 ks[240];
    __shared__ f32x4 vs[240];
    const int bid = blockIdx.x;
    const int wi  = bid / 120;
    const int g   = bid % 120;
    const int h   = g % 8;
    const int x   = (g / 8) * 16 + wi;
    const int t = threadIdx.x;

    const float scale = __expf(fminf(lsc[h], LOG_MAX_C));
    const float negM2 = -scale * LOG2E;
    f32x4 qreg[2] = {};

    if (t < 120) {
#pragma unroll
        for (int s = 0; s < 2; ++s) {
            const int jj = t + s * 120;
            const size_t pT = (((size_t)h * 240 + x) * 240 + jj) * 4;
            ks[jj] = *(const f32x4*)(knT + pT);
            vs[jj] = *(const f32x4*)(v1T + pT);
            qreg[s] = *(const f32x4*)(qnT + pT);
        }
    }
    __syncthreads();
    if (t < 120) {
        float l0 = 0.f, l1 = 0.f;
        f32x4 a0 = {0, 0, 0, 0}, a1 = {0, 0, 0, 0};
#pragma unroll 2
        for (int j = 0; j < 240; ++j) {
            const f32x4 kk = ks[j];
            const f32x4 vv = vs[j];
            const float s0 = fmaf(qreg[0][0], kk[0],
                             fmaf(qreg[0][1], kk[1],
                             fmaf(qreg[0][2], kk[2],
                             fmaf(qreg[0][3], kk[3], negM2))));
            const float s1 = fmaf(qreg[1][0], kk[0],
                             fmaf(qreg[1][1], kk[1],
                             fmaf(qreg[1][2], kk[2],
                             fmaf(qreg[1][3], kk[3], negM2))));
            const float p0 = EXP2F(s0);
            const float p1 = EXP2F(s1);
            l0 += p0; l1 += p1;
            a0 += vv * p0;
            a1 += vv * p1;
        }
        const float li0 = 1.0f / l0, li1 = 1.0f / l1;
#pragma unroll
        for (int s = 0; s < 2; ++s) {
            const f32x4 o4 = (s ? a1 * li1 : a0 * li0);
            const int i = t + s * 120;
            union { __bf16 h4[4]; uint2 u; } o;
#pragma unroll
            for (int d = 0; d < 4; ++d) o.h4[d] = (__bf16)o4[d];
            *(uint2*)(ys + (((size_t)(i + 1) * 3 + 2) * PW + x + 1) * 32 + h * 4) = o.u;
        }
    }
}

// ---------------------------------------------------------------------------
// Pipeline. Workspace (fp32 units):
//   xpk 96PP | xpv 96PP | fq4 96PP | xs/ys bf16 | wtf_in | wtf_f | wtf_o
// Aliases (b0/b1 slices of xpk/xpv/fq4 are dead after fused win_attn):
//   kn  = xpk b0 | qn  = xpk b1 | v1  = xpv b0
//   knT = xpv b1 | qnT = fq4 b0 | v1T = fq4 b1
// axial_row reads only b2 slices; transpose3 reads kn/qn/v1, writes *T;
// axial_col reads *T. Stream order guarantees safety.
// ---------------------------------------------------------------------------
extern "C" void kernel_launch(void* const* d_in, const int* in_sizes, int n_in,
                              void* d_out, int out_size, void* d_ws, size_t ws_size,
                              hipStream_t stream)
{
    const float* x     = (const float*)d_in[0];
    const float* w_in  = (const float*)d_in[1];
    const float* b_in  = (const float*)d_in[2];
    const float* w_f   = (const float*)d_in[3];
    const float* b_f   = (const float*)d_in[4];
    const float* w_out = (const float*)d_in[5];
    const float* b_out = (const float*)d_in[6];
    const float* lsc   = (const float*)d_in[7];
    const float* lrlsc = (const float*)d_in[8];
    float* out = (float*)d_out;

    float* ws  = (float*)d_ws;
    float* xpk = ws;                   // 96*PP
    float* xpv = xpk + 96 * PP;        // 96*PP
    float* fq4 = xpv + 96 * PP;        // 96*PP
    __bf16* xs     = (__bf16*)(fq4 + 96 * PP);            // 242*3*242*32 bf16
    __bf16* wtf_in = xs + (size_t)PW * 3 * PW * 32;
    __bf16* wtf_f  = wtf_in + 9 * 12 * 3 * 512;
    __bf16* wtf_o  = wtf_f + 9 * 6 * 3 * 512;
    __bf16* ys     = xs;               // alias: xs dead after conv_in/conv_f

    float* kn  = xpk;                  // b0, dead after fused win_attn
    float* qn  = xpk + 32 * PP;        // b1
    float* v1  = xpv;                  // b0
    float* knT = xpv + 32 * PP;        // b1
    float* qnT = fq4;                  // b0
    float* v1T = fq4 + 32 * PP;        // b1

    wt_frag<<<(9 * 12 * 3 * 64 + 255) / 256, 256, 0, stream>>>(w_in, wtf_in, 192);
    wt_frag<<<(9 * 6 * 3 * 64 + 255) / 256, 256, 0, stream>>>(w_f, wtf_f, 96);
    wt_frag<<<(9 * 6 * 3 * 64 + 255) / 256, 256, 0, stream>>>(w_out, wtf_o, 96);
    to_xs_pad<<<(PW * PW + 255) / 256, 256, 0, stream>>>(x, xs);

    conv3x3_mfma<192, 4, 1><<<1368, 256, 0, stream>>>(xs, wtf_in, b_in, xpk, xpv);
    conv3x3_mfma<96, 2, 2><<<1368, 256, 0, stream>>>(xs, wtf_f, b_f, fq4, nullptr);

    zero_border_xs<<<(4 * PW + 255) / 256, 256, 0, stream>>>(ys);

    // fused window attention (branches 0 + 1)
    win_attn_kernel<<<4608, 256, 0, stream>>>(fq4, xpk, xpv, lsc, ys);

    axial_row_kernel<<<dim3(240, 8), 128, 0, stream>>>(
        fq4 + 64 * PP, xpk + 64 * PP, xpv + 64 * PP, lrlsc, kn, qn, v1);
    transpose3<<<dim3(15, 15, 8), 256, 0, stream>>>(kn, qn, v1, knT, qnT, v1T);
    axial_col_kernel<<<1920, 128, 0, stream>>>(knT, qnT, v1T, lrlsc, ys);

    conv3x3_mfma<96, 2, 0><<<1368, 256, 0, stream>>>(ys, wtf_o, b_out, out, nullptr);
}